// Round 1
// 280.529 us; speedup vs baseline: 1.0206x; 1.0206x over previous
//
#include <hip/hip_runtime.h>
#include <hip/hip_fp16.h>
#include <math.h>

typedef _Float16 f16;
typedef _Float16 f16x8 __attribute__((ext_vector_type(8)));
typedef _Float16 f16x4 __attribute__((ext_vector_type(4)));
typedef float f32x4 __attribute__((ext_vector_type(4)));

namespace {
constexpr int kB = 32, kD = 512, kN = 1024, kF = 256;
constexpr float kScale = 0.04419417382415922f;   // 1/sqrt(512)
constexpr float kLogMarg = -6.931471805599453f;  // -log(1024)
constexpr float kMarg = 1.f / 1024.f;            // 1/n
constexpr float kPScale = 16384.f;               // 2^14: lift t into f16 range
constexpr float kPInv = 1.f / 16384.f;
}

// global -> LDS direct DMA, 16B per lane. LDS dest is wave-uniform base +
// lane*16 (hardware); global src is per-lane.
__device__ __forceinline__ void gload16(const void* g, void* l) {
  __builtin_amdgcn_global_load_lds(
      (const __attribute__((address_space(1))) void*)g,
      (__attribute__((address_space(3))) void*)l, 16, 0, 0);
}

// ---- K1: val = x[b,c,i] + pos(c,i); emit xfT[lb,c,i] and xf[lb,i,c] (f16) --
__global__ __launch_bounds__(256) void k_prep(
    const float* __restrict__ x, const float* __restrict__ re,
    const float* __restrict__ ce, f16* __restrict__ xf,
    f16* __restrict__ xfT, int b0) {
  __shared__ f16 T[64][68];
  const int lb = blockIdx.z;
  const int i0 = blockIdx.x * 64, c0 = blockIdx.y * 64;
  const int t = threadIdx.x;
  const int il = (t & 15) * 4;  // 0..60
  const int cl = t >> 4;        // 0..15
  const size_t xbase = ((size_t)(b0 + lb) * kD) * kN;
#pragma unroll
  for (int p = 0; p < 4; p++) {
    const int c = c0 + cl + 16 * p;
    const int i = i0 + il;
    const float4 xv = *(const float4*)(x + xbase + (size_t)c * kN + i);
    float4 pv;
    if (c < kF) {  // wave-uniform per block (c0 multiple of 64)
      pv.x = ce[((i + 0) & 31) * kF + c];
      pv.y = ce[((i + 1) & 31) * kF + c];
      pv.z = ce[((i + 2) & 31) * kF + c];
      pv.w = ce[((i + 3) & 31) * kF + c];
    } else {
      const float r = re[(i >> 5) * kF + (c - kF)];
      pv.x = r; pv.y = r; pv.z = r; pv.w = r;
    }
    const f16 h0 = (f16)(xv.x + pv.x), h1 = (f16)(xv.y + pv.y);
    const f16 h2 = (f16)(xv.z + pv.z), h3 = (f16)(xv.w + pv.w);
    f16* dT = xfT + ((size_t)lb * kD + c) * kN + i;
    *(f16x4*)dT = (f16x4){h0, h1, h2, h3};
    T[cl + 16 * p][il + 0] = h0; T[cl + 16 * p][il + 1] = h1;
    T[cl + 16 * p][il + 2] = h2; T[cl + 16 * p][il + 3] = h3;
  }
  __syncthreads();
#pragma unroll
  for (int p = 0; p < 4; p++) {
    const int ir = cl + 16 * p;  // local i
    const int cc = il;           // local c
    const f16 h0 = T[cc + 0][ir], h1 = T[cc + 1][ir];
    const f16 h2 = T[cc + 2][ir], h3 = T[cc + 3][ir];
    f16* dF = xf + ((size_t)lb * kN + i0 + ir) * kD + c0 + cc;
    *(f16x4*)dF = (f16x4){h0, h1, h2, h3};
  }
}

// ---- K2: S16 = f16(kScale * xf @ xf^T) (f16 MFMA, 128x128 tile, BK=64) -----
// m97 structure: global_load_lds(16B) into LINEAR [128][64]f16 LDS tiles;
// XOR swizzle (byte ^= (row&7)<<4) applied to the GLOBAL SOURCE address at
// stage time and to the ds_read_b128 address at read time (rule 21).
// Row partials of exp(S16) use the ROUNDED value, so u computed from them
// exactly cancels the diagonal's f16 rounding in pi = exp(S16+u+v).
__global__ __launch_bounds__(256) void k_gemm_s(
    const f16* __restrict__ xf, f16* __restrict__ S16,
    float* __restrict__ rp) {
  __shared__ char sm[32768];  // As [128][128B] | Bs [128][128B]
  const int lb = blockIdx.z;
  const int i0 = blockIdx.y * 128, j0 = blockIdx.x * 128;
  const char* base = (const char*)(xf + (size_t)lb * kN * kD);
  const int t = threadIdx.x;
  const int w = t >> 6, lane = t & 63;
  const int m_off = (w >> 1) * 64, n_off = (w & 1) * 64;
  const int quad = lane >> 4, l15 = lane & 15;
  const int swz = (l15 & 7) << 4;

  // staging: 4 chunks x (4 waves x 1KB). linear LDS off = p*4096+w*1024+lane*16
  int srcA[4], srcB[4], ldsw[4];
#pragma unroll
  for (int p = 0; p < 4; p++) {
    const int off = p * 4096 + w * 1024 + lane * 16;
    const int r = off >> 7;                       // tile row 0..127
    const int cb = (off & 127) ^ ((r & 7) << 4);  // inverse-swizzled src col
    srcA[p] = (i0 + r) * (kD * 2) + cb;           // row stride 1024 B
    srcB[p] = (j0 + r) * (kD * 2) + cb;
    ldsw[p] = p * 4096 + w * 1024;                // wave-uniform LDS base
  }

  f32x4 acc[4][4];
#pragma unroll
  for (int a = 0; a < 4; a++)
#pragma unroll
    for (int b = 0; b < 4; b++) acc[a][b] = (f32x4){0.f, 0.f, 0.f, 0.f};

  for (int k0b = 0; k0b < kD * 2; k0b += 128) {  // 128 B = 64 f16 per K-step
#pragma unroll
    for (int p = 0; p < 4; p++)
      gload16(base + srcA[p] + k0b, sm + ldsw[p]);
#pragma unroll
    for (int p = 0; p < 4; p++)
      gload16(base + srcB[p] + k0b, sm + 16384 + ldsw[p]);
    __syncthreads();  // drains vmcnt(0) -> LDS tiles ready
#pragma unroll
    for (int kk = 0; kk < 2; kk++) {
      f16x8 af[4], bf[4];
#pragma unroll
      for (int q = 0; q < 4; q++)
        af[q] = *(const f16x8*)(sm + (m_off + 16 * q + l15) * 128 +
                                ((kk * 64 + quad * 16) ^ swz));
#pragma unroll
      for (int q = 0; q < 4; q++)
        bf[q] = *(const f16x8*)(sm + 16384 + (n_off + 16 * q + l15) * 128 +
                                ((kk * 64 + quad * 16) ^ swz));
#pragma unroll
      for (int qa = 0; qa < 4; qa++)
#pragma unroll
        for (int qb = 0; qb < 4; qb++)
          acc[qa][qb] = __builtin_amdgcn_mfma_f32_16x16x32_f16(
              af[qa], bf[qb], acc[qa][qb], 0, 0, 0);
    }
    __syncthreads();  // before next-iter staging overwrites
  }

  f16* Sb = S16 + (size_t)lb * kN * kN;
  const int jt2 = blockIdx.x * 2 + (w & 1);
  float* rpb = rp + ((size_t)lb * 16 + jt2) * kN + i0 + m_off;
#pragma unroll
  for (int qa = 0; qa < 4; qa++) {
    const int i = i0 + m_off + 16 * qa + quad * 4;
    float rs[4] = {0.f, 0.f, 0.f, 0.f};
#pragma unroll
    for (int qb = 0; qb < 4; qb++) {
      const int j = j0 + n_off + 16 * qb + l15;
#pragma unroll
      for (int r = 0; r < 4; r++) {
        const f16 h = (f16)(acc[qa][qb][r] * kScale);
        Sb[(size_t)(i + r) * kN + j] = h;
        rs[r] += __expf((float)h);
      }
    }
#pragma unroll
    for (int r = 0; r < 4; r++) {
      float s = rs[r];
      s += __shfl_xor(s, 1);
      s += __shfl_xor(s, 2);
      s += __shfl_xor(s, 4);
      s += __shfl_xor(s, 8);
      if (l15 == 0) rpb[16 * qa + 4 * quad + r] = s;
    }
  }
}

// ---- K3: u[lb,i] = -log(n) - log(sum of 16 row partials) -------------------
__global__ __launch_bounds__(256) void k_u(
    const float* __restrict__ rp, float* __restrict__ u) {
  const int lb = blockIdx.y;
  const int i = blockIdx.x * 256 + threadIdx.x;
  const float* r = rp + (size_t)lb * 16 * kN + i;
  float s = 0.f;
#pragma unroll
  for (int t = 0; t < 16; t++) s += r[(size_t)t * kN];
  u[lb * kN + i] = kLogMarg - __logf(s);
}

// ---- K4: column partial sums of exp(S16 + u_i), 64 rows per seg ------------
__global__ __launch_bounds__(256) void k_cs(
    const f16* __restrict__ S16, const float* __restrict__ u,
    float* __restrict__ cp) {
  const int lb = blockIdx.z;
  const int seg = blockIdx.y;
  const int j = blockIdx.x * 256 + threadIdx.x;
  const f16* Sb = S16 + (size_t)lb * kN * kN + j;
  const float* ub = u + lb * kN + seg * 64;
  const size_t rbase = (size_t)(seg * 64) * kN;
  float s = 0.f;
#pragma unroll 4
  for (int r = 0; r < 64; r++)
    s += __expf((float)Sb[rbase + (size_t)r * kN] + ub[r]);
  cp[((size_t)lb * 16 + seg) * kN + j] = s;
}

// ---- K5: ev[lb,j] = exp(v_j) = (1/n) / colsum_j ----------------------------
__global__ __launch_bounds__(256) void k_v(
    const float* __restrict__ cp, float* __restrict__ ev) {
  const int lb = blockIdx.y;
  const int j = blockIdx.x * 256 + threadIdx.x;
  const float* c = cp + (size_t)lb * 16 * kN + j;
  float s = 0.f;
#pragma unroll
  for (int r = 0; r < 16; r++) s += c[(size_t)r * kN];
  ev[lb * kN + j] = kMarg / s;
}

// ---- K6: t16[i,j] = f16(2^14 * exp(S16 + u_i) * ev_j)  (= 2^14 * pi_ij) ----
__global__ __launch_bounds__(256) void k_pt(
    const f16* __restrict__ S16, const float* __restrict__ u,
    const float* __restrict__ ev, f16* __restrict__ t16) {
  const int row = blockIdx.x;  // lb*kN + i
  const float ui = u[row];
  const f16* Sr = S16 + (size_t)row * kN;
  const float* evb = ev + (size_t)(row >> 10) * kN;
  f16* Tr = t16 + (size_t)row * kN;
  const int j = threadIdx.x * 4;
  const f16x4 s = *(const f16x4*)(Sr + j);
  const float4 e = *(const float4*)(evb + j);
  f16x4 o;
  o[0] = (f16)(__expf((float)s[0] + ui) * e.x * kPScale);
  o[1] = (f16)(__expf((float)s[1] + ui) * e.y * kPScale);
  o[2] = (f16)(__expf((float)s[2] + ui) * e.z * kPScale);
  o[3] = (f16)(__expf((float)s[3] + ui) * e.w * kPScale);
  *(f16x4*)(Tr + j) = o;
}

// ---- K7: out[b,c,i] = (1/2^14) * sum_j xfT[c,j] * t16[i,j]  (f16 MFMA) -----
// Same m97 structure as k_gemm_s; row stride 2048 B, K = 1024.
__global__ __launch_bounds__(256) void k_gemm_o(
    const f16* __restrict__ xfT, const f16* __restrict__ P,
    float* __restrict__ out, int b0) {
  __shared__ char sm[32768];  // As [128][128B] | Bs [128][128B]
  const int lb = blockIdx.z;
  const int i0 = blockIdx.x * 128, c0 = blockIdx.y * 128;
  const char* Ab = (const char*)(xfT + (size_t)lb * kD * kN);
  const char* Bb = (const char*)(P + (size_t)lb * kN * kN);
  const int t = threadIdx.x;
  const int w = t >> 6, lane = t & 63;
  const int m_off = (w >> 1) * 64, n_off = (w & 1) * 64;
  const int quad = lane >> 4, l15 = lane & 15;
  const int swz = (l15 & 7) << 4;

  int srcA[4], srcB[4], ldsw[4];
#pragma unroll
  for (int p = 0; p < 4; p++) {
    const int off = p * 4096 + w * 1024 + lane * 16;
    const int r = off >> 7;
    const int cb = (off & 127) ^ ((r & 7) << 4);
    srcA[p] = (c0 + r) * (kN * 2) + cb;  // row stride 2048 B
    srcB[p] = (i0 + r) * (kN * 2) + cb;
    ldsw[p] = p * 4096 + w * 1024;
  }

  f32x4 acc[4][4];
#pragma unroll
  for (int a = 0; a < 4; a++)
#pragma unroll
    for (int b = 0; b < 4; b++) acc[a][b] = (f32x4){0.f, 0.f, 0.f, 0.f};

  for (int k0b = 0; k0b < kN * 2; k0b += 128) {
#pragma unroll
    for (int p = 0; p < 4; p++)
      gload16(Ab + srcA[p] + k0b, sm + ldsw[p]);
#pragma unroll
    for (int p = 0; p < 4; p++)
      gload16(Bb + srcB[p] + k0b, sm + 16384 + ldsw[p]);
    __syncthreads();
#pragma unroll
    for (int kk = 0; kk < 2; kk++) {
      f16x8 af[4], bf[4];
#pragma unroll
      for (int q = 0; q < 4; q++)
        af[q] = *(const f16x8*)(sm + (m_off + 16 * q + l15) * 128 +
                                ((kk * 64 + quad * 16) ^ swz));
#pragma unroll
      for (int q = 0; q < 4; q++)
        bf[q] = *(const f16x8*)(sm + 16384 + (n_off + 16 * q + l15) * 128 +
                                ((kk * 64 + quad * 16) ^ swz));
#pragma unroll
      for (int qa = 0; qa < 4; qa++)
#pragma unroll
        for (int qb = 0; qb < 4; qb++)
          acc[qa][qb] = __builtin_amdgcn_mfma_f32_16x16x32_f16(
              af[qa], bf[qb], acc[qa][qb], 0, 0, 0);
    }
    __syncthreads();
  }

  float* ob = out + ((size_t)(b0 + lb) * kD) * kN;
#pragma unroll
  for (int qa = 0; qa < 4; qa++) {
    const int c = c0 + m_off + 16 * qa + quad * 4;
#pragma unroll
    for (int qb = 0; qb < 4; qb++) {
      const int i = i0 + n_off + 16 * qb + l15;
#pragma unroll
      for (int r = 0; r < 4; r++)
        ob[(size_t)(c + r) * kN + i] = acc[qa][qb][r] * kPInv;
    }
  }
}

extern "C" void kernel_launch(void* const* d_in, const int* in_sizes, int n_in,
                              void* d_out, int out_size, void* d_ws, size_t ws_size,
                              hipStream_t stream) {
  const float* x = (const float*)d_in[0];
  const float* re = (const float*)d_in[1];
  const float* ce = (const float*)d_in[2];
  float* out = (float*)d_out;

  // ws per batch: S16 2MB + xf 1MB + xfT 1MB + t16 2MB + u 4KB + ev 4KB
  //             + rp 64KB + cp 64KB = ~6.13 MB. ws=256MiB -> G=32, ONE chunk.
  char* wsb = (char*)d_ws;
  const size_t perb = 2097152ull + 1048576 + 1048576 + 2097152 +
                      4096 + 4096 + 65536 + 65536;
  int G = (int)(ws_size / perb);
  if (G >= 32) G = 32;
  else if (G >= 16) G = 16;
  else if (G >= 8) G = 8;
  else if (G >= 4) G = 4;
  else if (G < 1) G = 1;
  f16* S16 = (f16*)wsb;
  f16* xf = (f16*)(wsb + (size_t)G * 2097152);
  f16* xfT = (f16*)((char*)xf + (size_t)G * 1048576);
  f16* t16 = (f16*)((char*)xfT + (size_t)G * 1048576);
  float* u = (float*)((char*)t16 + (size_t)G * 2097152);
  float* ev = u + (size_t)G * kN;
  float* rp = ev + (size_t)G * kN;            // [G][16][kN]
  float* cp = rp + (size_t)G * 16 * kN;       // [G][16][kN]

  for (int b0 = 0; b0 < kB; b0 += G) {
    const int g = (kB - b0 < G) ? (kB - b0) : G;
    k_prep<<<dim3(16, 8, g), 256, 0, stream>>>(x, re, ce, xf, xfT, b0);
    k_gemm_s<<<dim3(8, 8, g), 256, 0, stream>>>(xf, S16, rp);
    k_u<<<dim3(4, g), 256, 0, stream>>>(rp, u);
    k_cs<<<dim3(4, 16, g), 256, 0, stream>>>(S16, u, cp);
    k_v<<<dim3(4, g), 256, 0, stream>>>(cp, ev);
    k_pt<<<g * kN, 256, 0, stream>>>(S16, u, ev, t16);
    k_gemm_o<<<dim3(8, 4, g), 256, 0, stream>>>(xfT, t16, out, b0);
  }
}

// Round 2
// 256.142 us; speedup vs baseline: 1.1178x; 1.0952x over previous
//
#include <hip/hip_runtime.h>
#include <hip/hip_fp16.h>
#include <math.h>

typedef _Float16 f16;
typedef _Float16 f16x8 __attribute__((ext_vector_type(8)));
typedef _Float16 f16x4 __attribute__((ext_vector_type(4)));
typedef float f32x4 __attribute__((ext_vector_type(4)));

namespace {
constexpr int kB = 32, kD = 512, kN = 1024, kF = 256;
constexpr float kScale = 0.04419417382415922f;   // 1/sqrt(512)
constexpr float kLogMarg = -6.931471805599453f;  // -log(1024)
constexpr float kMarg = 1.f / 1024.f;            // 1/n
constexpr float kPScale = 16384.f;               // 2^14: lift t into f16 range
constexpr float kPInv = 1.f / 16384.f;
}

// global -> LDS direct DMA, 16B per lane. LDS dest is wave-uniform base +
// lane*16 (hardware); global src is per-lane.
__device__ __forceinline__ void gload16(const void* g, void* l) {
  __builtin_amdgcn_global_load_lds(
      (const __attribute__((address_space(1))) void*)g,
      (__attribute__((address_space(3))) void*)l, 16, 0, 0);
}

// ---- K1: val = x[b,c,i] + pos(c,i); emit xfT[lb,c,i] and xf[lb,i,c] (f16) --
__global__ __launch_bounds__(256) void k_prep(
    const float* __restrict__ x, const float* __restrict__ re,
    const float* __restrict__ ce, f16* __restrict__ xf,
    f16* __restrict__ xfT, int b0) {
  __shared__ f16 T[64][68];
  const int lb = blockIdx.z;
  const int i0 = blockIdx.x * 64, c0 = blockIdx.y * 64;
  const int t = threadIdx.x;
  const int il = (t & 15) * 4;  // 0..60
  const int cl = t >> 4;        // 0..15
  const size_t xbase = ((size_t)(b0 + lb) * kD) * kN;
#pragma unroll
  for (int p = 0; p < 4; p++) {
    const int c = c0 + cl + 16 * p;
    const int i = i0 + il;
    const float4 xv = *(const float4*)(x + xbase + (size_t)c * kN + i);
    float4 pv;
    if (c < kF) {  // wave-uniform per block (c0 multiple of 64)
      pv.x = ce[((i + 0) & 31) * kF + c];
      pv.y = ce[((i + 1) & 31) * kF + c];
      pv.z = ce[((i + 2) & 31) * kF + c];
      pv.w = ce[((i + 3) & 31) * kF + c];
    } else {
      const float r = re[(i >> 5) * kF + (c - kF)];
      pv.x = r; pv.y = r; pv.z = r; pv.w = r;
    }
    const f16 h0 = (f16)(xv.x + pv.x), h1 = (f16)(xv.y + pv.y);
    const f16 h2 = (f16)(xv.z + pv.z), h3 = (f16)(xv.w + pv.w);
    f16* dT = xfT + ((size_t)lb * kD + c) * kN + i;
    *(f16x4*)dT = (f16x4){h0, h1, h2, h3};
    T[cl + 16 * p][il + 0] = h0; T[cl + 16 * p][il + 1] = h1;
    T[cl + 16 * p][il + 2] = h2; T[cl + 16 * p][il + 3] = h3;
  }
  __syncthreads();
#pragma unroll
  for (int p = 0; p < 4; p++) {
    const int ir = cl + 16 * p;  // local i
    const int cc = il;           // local c
    const f16 h0 = T[cc + 0][ir], h1 = T[cc + 1][ir];
    const f16 h2 = T[cc + 2][ir], h3 = T[cc + 3][ir];
    f16* dF = xf + ((size_t)lb * kN + i0 + ir) * kD + c0 + cc;
    *(f16x4*)dF = (f16x4){h0, h1, h2, h3};
  }
}

// ---- K2: S16 = f16(kScale * xf @ xf^T) (f16 MFMA, 128x128 tile, BK=64) -----
// 2-deep double-buffered pipeline: issue next K-tile's global_load_lds FIRST,
// then ds_read+MFMA current tile, then ONE __syncthreads per K-step (its
// vmcnt drain lands after compute has covered the load latency).
// T2 XOR swizzle on global source + ds_read addr (rule 21); LDS dest linear.
// T1 bijective XCD-chunked block swizzle: each XCD gets contiguous work-ids
// -> ~1MB/batch L2 working set instead of all-batch A panels.
__global__ __launch_bounds__(256) void k_gemm_s(
    const f16* __restrict__ xf, f16* __restrict__ S16,
    float* __restrict__ rp) {
  __shared__ char sm[65536];  // buf0: A[0:16K) B[16K:32K); buf1: +32K
  // --- XCD-chunked swizzle (nwg = 64*g, always %8==0) ---
  const int nwg = (int)(gridDim.x * gridDim.y * gridDim.z);
  const int lin = (int)(blockIdx.x +
                        gridDim.x * (blockIdx.y + gridDim.y * blockIdx.z));
  const int wid = (lin & 7) * (nwg >> 3) + (lin >> 3);
  const int bx = wid & 7, by = (wid >> 3) & 7, bz = wid >> 6;

  const int lb = bz;
  const int i0 = by * 128, j0 = bx * 128;
  const char* base = (const char*)(xf + (size_t)lb * kN * kD);
  const int t = threadIdx.x;
  const int w = t >> 6, lane = t & 63;
  const int m_off = (w >> 1) * 64, n_off = (w & 1) * 64;
  const int quad = lane >> 4, l15 = lane & 15;
  const int swz = (l15 & 7) << 4;

  // staging: 4 chunks x (4 waves x 1KB). linear LDS off = p*4096+w*1024+lane*16
  int srcA[4], srcB[4], ldsw[4];
#pragma unroll
  for (int p = 0; p < 4; p++) {
    const int off = p * 4096 + w * 1024 + lane * 16;
    const int r = off >> 7;                       // tile row 0..127
    const int cb = (off & 127) ^ ((r & 7) << 4);  // inverse-swizzled src col
    srcA[p] = (i0 + r) * (kD * 2) + cb;           // row stride 1024 B
    srcB[p] = (j0 + r) * (kD * 2) + cb;
    ldsw[p] = p * 4096 + w * 1024;                // wave-uniform LDS base
  }

  f32x4 acc[4][4];
#pragma unroll
  for (int a = 0; a < 4; a++)
#pragma unroll
    for (int b = 0; b < 4; b++) acc[a][b] = (f32x4){0.f, 0.f, 0.f, 0.f};

  // prologue: stage K-tile 0 into buf0
#pragma unroll
  for (int p = 0; p < 4; p++) gload16(base + srcA[p], sm + ldsw[p]);
#pragma unroll
  for (int p = 0; p < 4; p++) gload16(base + srcB[p], sm + 16384 + ldsw[p]);
  __syncthreads();

#pragma unroll
  for (int tt = 0; tt < 8; tt++) {  // 8 K-tiles of 64 f16 (128 B)
    const int cur = tt & 1, nxt = cur ^ 1;
    if (tt + 1 < 8) {  // issue next tile's loads FIRST (overlap with compute)
      const int k0b = (tt + 1) * 128;
#pragma unroll
      for (int p = 0; p < 4; p++)
        gload16(base + srcA[p] + k0b, sm + (nxt << 15) + ldsw[p]);
#pragma unroll
      for (int p = 0; p < 4; p++)
        gload16(base + srcB[p] + k0b, sm + (nxt << 15) + 16384 + ldsw[p]);
    }
    const char* bA = sm + (cur << 15);
    const char* bB = bA + 16384;
#pragma unroll
    for (int kk = 0; kk < 2; kk++) {
      f16x8 af[4], bf[4];
#pragma unroll
      for (int q = 0; q < 4; q++)
        af[q] = *(const f16x8*)(bA + (m_off + 16 * q + l15) * 128 +
                                ((kk * 64 + quad * 16) ^ swz));
#pragma unroll
      for (int q = 0; q < 4; q++)
        bf[q] = *(const f16x8*)(bB + (n_off + 16 * q + l15) * 128 +
                                ((kk * 64 + quad * 16) ^ swz));
#pragma unroll
      for (int qa = 0; qa < 4; qa++)
#pragma unroll
        for (int qb = 0; qb < 4; qb++)
          acc[qa][qb] = __builtin_amdgcn_mfma_f32_16x16x32_f16(
              af[qa], bf[qb], acc[qa][qb], 0, 0, 0);
    }
    __syncthreads();  // drains vmcnt (next tile ready) + protects cur reuse
  }

  f16* Sb = S16 + (size_t)lb * kN * kN;
  const int jt2 = bx * 2 + (w & 1);
  float* rpb = rp + ((size_t)lb * 16 + jt2) * kN + i0 + m_off;
#pragma unroll
  for (int qa = 0; qa < 4; qa++) {
    const int i = i0 + m_off + 16 * qa + quad * 4;
    float rs[4] = {0.f, 0.f, 0.f, 0.f};
#pragma unroll
    for (int qb = 0; qb < 4; qb++) {
      const int j = j0 + n_off + 16 * qb + l15;
#pragma unroll
      for (int r = 0; r < 4; r++) {
        const f16 h = (f16)(acc[qa][qb][r] * kScale);
        Sb[(size_t)(i + r) * kN + j] = h;
        rs[r] += __expf((float)h);
      }
    }
#pragma unroll
    for (int r = 0; r < 4; r++) {
      float s = rs[r];
      s += __shfl_xor(s, 1);
      s += __shfl_xor(s, 2);
      s += __shfl_xor(s, 4);
      s += __shfl_xor(s, 8);
      if (l15 == 0) rpb[16 * qa + 4 * quad + r] = s;
    }
  }
}

// ---- K3: u[lb,i] = -log(n) - log(sum of 16 row partials) -------------------
__global__ __launch_bounds__(256) void k_u(
    const float* __restrict__ rp, float* __restrict__ u) {
  const int lb = blockIdx.y;
  const int i = blockIdx.x * 256 + threadIdx.x;
  const float* r = rp + (size_t)lb * 16 * kN + i;
  float s = 0.f;
#pragma unroll
  for (int t = 0; t < 16; t++) s += r[(size_t)t * kN];
  u[lb * kN + i] = kLogMarg - __logf(s);
}

// ---- K4: column partial sums of exp(S16 + u_i), 64 rows per seg ------------
__global__ __launch_bounds__(256) void k_cs(
    const f16* __restrict__ S16, const float* __restrict__ u,
    float* __restrict__ cp) {
  const int lb = blockIdx.z;
  const int seg = blockIdx.y;
  const int j = blockIdx.x * 256 + threadIdx.x;
  const f16* Sb = S16 + (size_t)lb * kN * kN + j;
  const float* ub = u + lb * kN + seg * 64;
  const size_t rbase = (size_t)(seg * 64) * kN;
  float s = 0.f;
#pragma unroll 4
  for (int r = 0; r < 64; r++)
    s += __expf((float)Sb[rbase + (size_t)r * kN] + ub[r]);
  cp[((size_t)lb * 16 + seg) * kN + j] = s;
}

// ---- K5: ev[lb,j] = exp(v_j) = (1/n) / colsum_j ----------------------------
__global__ __launch_bounds__(256) void k_v(
    const float* __restrict__ cp, float* __restrict__ ev) {
  const int lb = blockIdx.y;
  const int j = blockIdx.x * 256 + threadIdx.x;
  const float* c = cp + (size_t)lb * 16 * kN + j;
  float s = 0.f;
#pragma unroll
  for (int r = 0; r < 16; r++) s += c[(size_t)r * kN];
  ev[lb * kN + j] = kMarg / s;
}

// ---- K6: t16[i,j] = f16(2^14 * exp(S16 + u_i) * ev_j)  (= 2^14 * pi_ij) ----
__global__ __launch_bounds__(256) void k_pt(
    const f16* __restrict__ S16, const float* __restrict__ u,
    const float* __restrict__ ev, f16* __restrict__ t16) {
  const int row = blockIdx.x;  // lb*kN + i
  const float ui = u[row];
  const f16* Sr = S16 + (size_t)row * kN;
  const float* evb = ev + (size_t)(row >> 10) * kN;
  f16* Tr = t16 + (size_t)row * kN;
  const int j = threadIdx.x * 4;
  const f16x4 s = *(const f16x4*)(Sr + j);
  const float4 e = *(const float4*)(evb + j);
  f16x4 o;
  o[0] = (f16)(__expf((float)s[0] + ui) * e.x * kPScale);
  o[1] = (f16)(__expf((float)s[1] + ui) * e.y * kPScale);
  o[2] = (f16)(__expf((float)s[2] + ui) * e.z * kPScale);
  o[3] = (f16)(__expf((float)s[3] + ui) * e.w * kPScale);
  *(f16x4*)(Tr + j) = o;
}

// ---- K7: out[b,c,i] = (1/2^14) * sum_j xfT[c,j] * t16[i,j]  (f16 MFMA) -----
// Same 2-deep pipeline + XCD swizzle as k_gemm_s; row stride 2048 B, K=1024.
__global__ __launch_bounds__(256) void k_gemm_o(
    const f16* __restrict__ xfT, const f16* __restrict__ P,
    float* __restrict__ out, int b0) {
  __shared__ char sm[65536];
  const int nwg = (int)(gridDim.x * gridDim.y * gridDim.z);
  const int lin = (int)(blockIdx.x +
                        gridDim.x * (blockIdx.y + gridDim.y * blockIdx.z));
  const int wid = (lin & 7) * (nwg >> 3) + (lin >> 3);
  const int bx = wid & 7, by = (wid >> 3) & 3, bz = wid >> 5;

  const int lb = bz;
  const int i0 = bx * 128, c0 = by * 128;
  const char* Ab = (const char*)(xfT + (size_t)lb * kD * kN);
  const char* Bb = (const char*)(P + (size_t)lb * kN * kN);
  const int t = threadIdx.x;
  const int w = t >> 6, lane = t & 63;
  const int m_off = (w >> 1) * 64, n_off = (w & 1) * 64;
  const int quad = lane >> 4, l15 = lane & 15;
  const int swz = (l15 & 7) << 4;

  int srcA[4], srcB[4], ldsw[4];
#pragma unroll
  for (int p = 0; p < 4; p++) {
    const int off = p * 4096 + w * 1024 + lane * 16;
    const int r = off >> 7;
    const int cb = (off & 127) ^ ((r & 7) << 4);
    srcA[p] = (c0 + r) * (kN * 2) + cb;  // row stride 2048 B
    srcB[p] = (i0 + r) * (kN * 2) + cb;
    ldsw[p] = p * 4096 + w * 1024;
  }

  f32x4 acc[4][4];
#pragma unroll
  for (int a = 0; a < 4; a++)
#pragma unroll
    for (int b = 0; b < 4; b++) acc[a][b] = (f32x4){0.f, 0.f, 0.f, 0.f};

  // prologue: stage K-tile 0 into buf0
#pragma unroll
  for (int p = 0; p < 4; p++) gload16(Ab + srcA[p], sm + ldsw[p]);
#pragma unroll
  for (int p = 0; p < 4; p++) gload16(Bb + srcB[p], sm + 16384 + ldsw[p]);
  __syncthreads();

#pragma unroll
  for (int tt = 0; tt < 16; tt++) {  // 16 K-tiles of 64 f16
    const int cur = tt & 1, nxt = cur ^ 1;
    if (tt + 1 < 16) {
      const int k0b = (tt + 1) * 128;
#pragma unroll
      for (int p = 0; p < 4; p++)
        gload16(Ab + srcA[p] + k0b, sm + (nxt << 15) + ldsw[p]);
#pragma unroll
      for (int p = 0; p < 4; p++)
        gload16(Bb + srcB[p] + k0b, sm + (nxt << 15) + 16384 + ldsw[p]);
    }
    const char* bA = sm + (cur << 15);
    const char* bB = bA + 16384;
#pragma unroll
    for (int kk = 0; kk < 2; kk++) {
      f16x8 af[4], bf[4];
#pragma unroll
      for (int q = 0; q < 4; q++)
        af[q] = *(const f16x8*)(bA + (m_off + 16 * q + l15) * 128 +
                                ((kk * 64 + quad * 16) ^ swz));
#pragma unroll
      for (int q = 0; q < 4; q++)
        bf[q] = *(const f16x8*)(bB + (n_off + 16 * q + l15) * 128 +
                                ((kk * 64 + quad * 16) ^ swz));
#pragma unroll
      for (int qa = 0; qa < 4; qa++)
#pragma unroll
        for (int qb = 0; qb < 4; qb++)
          acc[qa][qb] = __builtin_amdgcn_mfma_f32_16x16x32_f16(
              af[qa], bf[qb], acc[qa][qb], 0, 0, 0);
    }
    __syncthreads();
  }

  float* ob = out + ((size_t)(b0 + lb) * kD) * kN;
#pragma unroll
  for (int qa = 0; qa < 4; qa++) {
    const int c = c0 + m_off + 16 * qa + quad * 4;
#pragma unroll
    for (int qb = 0; qb < 4; qb++) {
      const int i = i0 + n_off + 16 * qb + l15;
#pragma unroll
      for (int r = 0; r < 4; r++)
        ob[(size_t)(c + r) * kN + i] = acc[qa][qb][r] * kPInv;
    }
  }
}

extern "C" void kernel_launch(void* const* d_in, const int* in_sizes, int n_in,
                              void* d_out, int out_size, void* d_ws, size_t ws_size,
                              hipStream_t stream) {
  const float* x = (const float*)d_in[0];
  const float* re = (const float*)d_in[1];
  const float* ce = (const float*)d_in[2];
  float* out = (float*)d_out;

  // ws per batch: S16 2MB + xf 1MB + xfT 1MB + t16 2MB + u 4KB + ev 4KB
  //             + rp 64KB + cp 64KB = ~6.13 MB. ws=256MiB -> G=32, ONE chunk.
  char* wsb = (char*)d_ws;
  const size_t perb = 2097152ull + 1048576 + 1048576 + 2097152 +
                      4096 + 4096 + 65536 + 65536;
  int G = (int)(ws_size / perb);
  if (G >= 32) G = 32;
  else if (G >= 16) G = 16;
  else if (G >= 8) G = 8;
  else if (G >= 4) G = 4;
  else if (G < 1) G = 1;
  f16* S16 = (f16*)wsb;
  f16* xf = (f16*)(wsb + (size_t)G * 2097152);
  f16* xfT = (f16*)((char*)xf + (size_t)G * 1048576);
  f16* t16 = (f16*)((char*)xfT + (size_t)G * 1048576);
  float* u = (float*)((char*)t16 + (size_t)G * 2097152);
  float* ev = u + (size_t)G * kN;
  float* rp = ev + (size_t)G * kN;            // [G][16][kN]
  float* cp = rp + (size_t)G * 16 * kN;       // [G][16][kN]

  for (int b0 = 0; b0 < kB; b0 += G) {
    const int g = (kB - b0 < G) ? (kB - b0) : G;
    k_prep<<<dim3(16, 8, g), 256, 0, stream>>>(x, re, ce, xf, xfT, b0);
    k_gemm_s<<<dim3(8, 8, g), 256, 0, stream>>>(xf, S16, rp);
    k_u<<<dim3(4, g), 256, 0, stream>>>(rp, u);
    k_cs<<<dim3(4, 16, g), 256, 0, stream>>>(S16, u, cp);
    k_v<<<dim3(4, g), 256, 0, stream>>>(cp, ev);
    k_pt<<<g * kN, 256, 0, stream>>>(S16, u, ev, t16);
    k_gemm_o<<<dim3(8, 4, g), 256, 0, stream>>>(xfT, t16, out, b0);
  }
}